// Round 1
// 151.480 us; speedup vs baseline: 1.1910x; 1.1910x over previous
//
#include <hip/hip_runtime.h>
#include <stdint.h>

typedef unsigned long long u64;

#define N 8192
#define NW 128            // 64-bit words per mask row
#define MAX_OUT 256
#define MASK_BYTES ((size_t)N * NW * 8)   // 8 MiB

// ws layout:
//   [0, 8MB)    mask u64[N][NW]
//     overlap (dead before mask_kernel writes):
//       ws+0      keys u64[N]   (64 KB)   written by build_keys, read by rank
//       ws+64KB   rank int[N]   (32 KB)   zeroed by build_keys, atomicAdd by rank, read by scatter
//   +8MB        order  int[N]     32 KB
//   +32KB       s_s    float[N]   32 KB
//   +64KB       bbox   float4[N] 128 KB
//   +192KB      area   float[N]   32 KB
//   +224KB      nvalid int        (memset to 0 each launch)

// ---------------- Kernel A: build sort keys + zero ranks + count valid ----------------
// key = (~score_bits << 32) | idx → ascending == score desc, idx asc (stable).
// Valid count folded in (sorted desc ⇒ valid is a prefix of length nvalid).
__global__ __launch_bounds__(256)
void build_keys_kernel(const float* __restrict__ score, u64* __restrict__ keys,
                       int* __restrict__ rank, int* __restrict__ nvalid) {
    int i = blockIdx.x * 256 + threadIdx.x;
    float s = score[i];
    uint32_t b = __float_as_uint(s);
    keys[i] = ((u64)(~b) << 32) | (uint32_t)i;
    rank[i] = 0;
    int c = (s >= 0.3f) ? 1 : 0;
    for (int off = 32; off; off >>= 1) c += __shfl_down(c, off);
    __shared__ int part[4];
    if ((threadIdx.x & 63) == 0) part[threadIdx.x >> 6] = c;
    __syncthreads();
    if (threadIdx.x == 0) atomicAdd(nvalid, part[0] + part[1] + part[2] + part[3]);
}

// ---------------- Kernel B: rank = #{j : key[j] < key[i]} ----------------
__global__ __launch_bounds__(256)
void rank_kernel(const u64* __restrict__ keys, int* __restrict__ rank) {
    __shared__ u64 kj[1024];
    const int tid = threadIdx.x;
    const int jbase = blockIdx.y * 1024;
    for (int t = tid; t < 1024; t += 256) kj[t] = keys[jbase + t];
    __syncthreads();
    const int i = blockIdx.x * 256 + tid;
    const u64 ki = keys[i];
    int c = 0;
    #pragma unroll 8
    for (int j = 0; j < 1024; ++j) c += (kj[j] < ki) ? 1 : 0;
    atomicAdd(&rank[i], c);
}

// ---------------- Kernel C: scatter to sorted order + precompute ----------------
__global__ __launch_bounds__(256)
void scatter_kernel(const float* __restrict__ score, const float* __restrict__ box,
                    const int* __restrict__ rank, int* __restrict__ order,
                    float* __restrict__ s_s, float4* __restrict__ bbox,
                    float* __restrict__ area) {
    int i = blockIdx.x * 256 + threadIdx.x;
    int r = rank[i];
    float s = score[i];
    order[r] = i;
    s_s[r] = s;
    float4 cb = ((const float4*)box)[i * 4];   // box row = 16 f32; first 4 = cx,cy,w,h
    float hw = cb.z * 0.5f, hh = cb.w * 0.5f;
    float x0 = cb.x - hw, y0 = cb.y - hh, x1 = cb.x + hw, y1 = cb.y + hh;
    bbox[r] = make_float4(x0, y0, x1, y1);
    area[r] = (x1 - x0) * (y1 - y0);   // replicate ref: area from xyxy
}

// ---------------- Kernel 2: suppression bitmask (upper triangle) ----------------
__global__ __launch_bounds__(256)
void mask_kernel(const float4* __restrict__ bbox, const float* __restrict__ area,
                 const int* __restrict__ nvalid_p, u64* __restrict__ mask) {
    const int w = blockIdx.x;
    const int i = blockIdx.y * 256 + threadIdx.x;
    __shared__ float4 jb[64];
    __shared__ float  ja[64];
    if (threadIdx.x < 64) {
        jb[threadIdx.x] = bbox[w * 64 + threadIdx.x];
        ja[threadIdx.x] = area[w * 64 + threadIdx.x];
    }
    __syncthreads();
    const int nv = *nvalid_p;
    if (i >= nv) return;
    if (w < (i >> 6)) return;
    float4 a = bbox[i];
    float  aa = area[i];
    u64 bits = 0;
    #pragma unroll 8
    for (int jj = 0; jj < 64; ++jj) {
        float4 b = jb[jj];
        float lx = fmaxf(a.x, b.x), ly = fmaxf(a.y, b.y);
        float rx = fminf(a.z, b.z), ry = fminf(a.w, b.w);
        float ww = fmaxf(rx - lx, 0.0f), hh = fmaxf(ry - ly, 0.0f);
        float inter = ww * hh;
        float denom = ((aa + ja[jj]) - inter) + 1e-9f;  // exact ref op order
        float iou = inter / denom;                       // IEEE div, matches np
        bits |= ((u64)(iou > 0.3f)) << jj;
    }
    mask[(size_t)i * NW + w] = bits;
}

// ---------------- Kernel 3: serial greedy pass, fully pipelined ----------------
// Column formulation: no remv maintenance, no data-dependent loads on the
// critical path. Suppression word for block b is assembled from:
//   - gathers mask[kpos[t]][b]     (kept known 2 blocks ago; issued 2 ahead)
//   - spec rows mask[base_{b-1}+l][b] masked by km_{b-1}   (s1m, registers)
//   - spec rows mask[base_{b-2}+l][b] masked by km_{b-2}   (s2m_old, registers)
// combined with one 6-step shfl_xor OR-butterfly. All loads are issued 2
// blocks ahead of consumption (static addresses, or kept-set-by-definition),
// so HBM/L3 latency overlaps the ~400cy of ALU per block.

struct Pipe { u64 col, s1, s2, g0, g1, g2, g3; };

__device__ __forceinline__ u64 wave_or64(u64 v) {
    unsigned lo = (unsigned)v, hi = (unsigned)(v >> 32);
    #pragma unroll
    for (int off = 1; off < 64; off <<= 1) {
        lo |= (unsigned)__shfl_xor((int)lo, off, 64);
        hi |= (unsigned)__shfl_xor((int)hi, off, 64);
    }
    return ((u64)hi << 32) | (u64)lo;
}

__global__ __launch_bounds__(64)
void nms_kernel(const u64* __restrict__ mask, const float* __restrict__ s_s,
                const int* __restrict__ order, const float* __restrict__ box,
                const int* __restrict__ nvalid_p, float* __restrict__ out) {
    const int lane = threadIdx.x;
    const int nv = *nvalid_p;
    const int nblk = (nv + 63) >> 6;
    __shared__ int kpos[MAX_OUT];
    int kcount = 0;
    u64 s1m = 0, s2m = 0, s2m_old = 0;

    // prologue: fill pipeline sets for blocks 0 (A) and 1 (B)
    Pipe A, B;
    A.col = A.s1 = A.s2 = A.g0 = A.g1 = A.g2 = A.g3 = 0;
    B.col = B.s1 = B.s2 = B.g0 = B.g1 = B.g2 = B.g3 = 0;
    if (nblk > 0) {
        const u64* r = mask + (size_t)lane * NW;
        A.col = r[0];
        if (nblk > 1) A.s1 = r[1];
        if (nblk > 2) A.s2 = r[2];
    }
    if (nblk > 1) {
        const u64* r = mask + (size_t)(64 + lane) * NW;
        B.col = r[1];
        if (nblk > 2) B.s1 = r[2];
        if (nblk > 3) B.s2 = r[3];
    }

    auto step = [&](int b, Pipe& P) -> bool {
        // consume P (compiler inserts the vmcnt wait here), copy to locals
        u64 col = P.col, s1v = P.s1, s2v = P.s2;
        u64 x = P.g0 | P.g1 | P.g2 | P.g3 | s1m | s2m_old;
        // reissue P for block b+2 (before the butterfly so loads fly early)
        const int b2 = b + 2;
        P.col = P.s1 = P.s2 = P.g0 = P.g1 = P.g2 = P.g3 = 0;
        if (b2 < nblk) {
            const u64* r = mask + (size_t)((b2 << 6) + lane) * NW;
            P.col = r[b2];                       // diagonal word (upper tri ok)
            if (b2 + 1 < nblk) P.s1 = r[b2 + 1];
            if (b2 + 2 < nblk) P.s2 = r[b2 + 2];
            const int kc = kcount;               // kept set K_{<b} by definition
            if (lane < kc)       P.g0 = mask[(size_t)kpos[lane]       * NW + b2];
            if (lane +  64 < kc) P.g1 = mask[(size_t)kpos[lane +  64] * NW + b2];
            if (lane + 128 < kc) P.g2 = mask[(size_t)kpos[lane + 128] * NW + b2];
            if (lane + 192 < kc) P.g3 = mask[(size_t)kpos[lane + 192] * NW + b2];
        }
        // suppression word for this block: OR across all 64 lanes
        u64 rw = wave_or64(x);
        const int base = b << 6;
        const int rem = nv - base;               // >= 1 since b < nblk
        u64 validm = (rem >= 64) ? ~0ull : ((1ull << rem) - 1ull);
        u64 todo = validm & ~rw;
        u64 km = 0;
        while (todo) {
            int l = (int)__builtin_ctzll(todo);
            u64 row_l = __ballot(((col >> l) & 1ull) != 0);  // in-tile row via symmetry
            if (lane == 0) kpos[kcount] = base + l;
            km |= (1ull << l);
            kcount++;
            todo &= ~row_l;
            todo &= ~(1ull << l);
            if (kcount >= MAX_OUT) break;
        }
        // register-only contributions of this block's kept to blocks b+1, b+2
        u64 keepm = ((km >> lane) & 1ull) ? ~0ull : 0ull;
        s2m_old = s2m;
        s2m = s2v & keepm;   // word b+2 contribution
        s1m = s1v & keepm;   // word b+1 contribution
        return kcount < MAX_OUT;
    };

    bool run = true;
    for (int b = 0; run && b < nblk; b += 2) {
        run = step(b, A);
        if (run && b + 1 < nblk) run = step(b + 1, B);
    }

    __syncthreads();
    // outputs: [score 256][box 256*16][valid 256], all float32
    float* out_score = out;
    float* out_box   = out + MAX_OUT;
    float* out_valid = out + MAX_OUT + MAX_OUT * 16;
    const float4* box4 = (const float4*)box;
    float4* ob4 = (float4*)out_box;
    for (int t = lane; t < MAX_OUT; t += 64) {
        if (t < kcount) {
            int p = kpos[t];
            out_score[t] = s_s[p];
            out_valid[t] = 1.0f;
            int oi = order[p];
            #pragma unroll
            for (int q = 0; q < 4; ++q) ob4[t * 4 + q] = box4[oi * 4 + q];
        } else {
            out_score[t] = 0.0f;
            out_valid[t] = 0.0f;
            float4 z = make_float4(0.f, 0.f, 0.f, 0.f);
            #pragma unroll
            for (int q = 0; q < 4; ++q) ob4[t * 4 + q] = z;
        }
    }
}

extern "C" void kernel_launch(void* const* d_in, const int* in_sizes, int n_in,
                              void* d_out, int out_size, void* d_ws, size_t ws_size,
                              hipStream_t stream) {
    const float* score = (const float*)d_in[0];   // (8192,1) f32
    const float* box   = (const float*)d_in[1];   // (8192,16) f32
    char* ws = (char*)d_ws;
    u64*    mask   = (u64*)ws;
    // overlap region (dead before mask_kernel):
    u64*    keys   = (u64*)ws;                    // 64 KB
    int*    rank   = (int*)(ws + 65536);          // 32 KB
    // persistent region:
    int*    order  = (int*)   (ws + MASK_BYTES);
    float*  s_s    = (float*) (ws + MASK_BYTES + 32768);
    float4* bbox   = (float4*)(ws + MASK_BYTES + 65536);
    float*  area   = (float*) (ws + MASK_BYTES + 65536 + 131072);
    int*    nvalid = (int*)   (ws + MASK_BYTES + 65536 + 131072 + 32768);

    hipMemsetAsync(nvalid, 0, sizeof(int), stream);
    build_keys_kernel<<<32, 256, 0, stream>>>(score, keys, rank, nvalid);
    rank_kernel<<<dim3(32, 8), 256, 0, stream>>>(keys, rank);
    scatter_kernel<<<32, 256, 0, stream>>>(score, box, rank, order, s_s, bbox, area);
    mask_kernel<<<dim3(128, 32), 256, 0, stream>>>(bbox, area, nvalid, mask);
    nms_kernel<<<1, 64, 0, stream>>>(mask, s_s, order, box, nvalid, (float*)d_out);
}